// Round 1
// 421.911 us; speedup vs baseline: 1.1621x; 1.1621x over previous
//
#include <hip/hip_runtime.h>

using u16 = unsigned short;
typedef __bf16 bf16x8 __attribute__((ext_vector_type(8)));
typedef u16    u16x8  __attribute__((ext_vector_type(8)));
typedef u16    u16x4  __attribute__((ext_vector_type(4)));
typedef float  f32x4  __attribute__((ext_vector_type(4)));
typedef float  f32x16 __attribute__((ext_vector_type(16)));
typedef unsigned uint4v __attribute__((ext_vector_type(4)));

#define DEV static __device__ __forceinline__

constexpr int NB = 4;          // batch
constexpr int NN = 20000;      // tokens
constexpr int DD = 64;         // model dim
constexpr int KK = 256;        // linformer K
constexpr int ROWS = NB * NN;  // 80000 flat rows

DEV float b2f(u16 u) { union { unsigned i; float f; } c; c.i = ((unsigned)u) << 16; return c.f; }
DEV u16 f2b(float f) {
  union { float f; unsigned i; } c; c.f = f;
  unsigned i = c.i + 0x7FFFu + ((c.i >> 16) & 1u);
  return (u16)(i >> 16);
}
DEV bf16x8 ldb8(const u16* p) { return *reinterpret_cast<const bf16x8*>(p); }
DEV f32x16 mfma32(bf16x8 a, bf16x8 b, f32x16 c) { return __builtin_amdgcn_mfma_f32_32x32x16_bf16(a, b, c, 0, 0, 0); }

// pack two f32 -> one u32 of 2 bf16 (elem0 = lo, elem1 = hi), RNE
DEV unsigned cvtpk(float lo, float hi) {
  unsigned r;
  asm("v_cvt_pk_bf16_f32 %0, %1, %2" : "=v"(r) : "v"(lo), "v"(hi));
  return r;
}
// exchange: a' = [a.lo32 | b.lo32], b' = [a.hi32 | b.hi32]
DEV void swap32(unsigned& a, unsigned& b) {
  auto r = __builtin_amdgcn_permlane32_swap((int)a, (int)b, false, false);
  a = (unsigned)r[0]; b = (unsigned)r[1];
}

// ---------------------------------------------------------------------------
// Merged preamble: [0,5008) transpose projK/projV -> bf16 [K][N];
// [5008,7508) embed; [7508,7572) weight fragment conversion; [7572] ones fill.
__global__ __launch_bounds__(256) void k_pre(
    const float* __restrict__ expr, const float* __restrict__ emb,
    const float* __restrict__ Wq, const float* __restrict__ Wo,
    const float* __restrict__ W1, const float* __restrict__ W2,
    const float* __restrict__ projK, const float* __restrict__ projV,
    u16* __restrict__ wb, u16* __restrict__ pKT, u16* __restrict__ pVT,
    u16* __restrict__ xb, u16* __restrict__ ones) {
  __shared__ float lds[64][65];
  int bid = blockIdx.x;
  int t = threadIdx.x;
  if (bid < 5008) {
    // ---- transpose [L][N][K] f32 -> [L][K][N] bf16
    int nt = bid % 313, q = bid / 313, kt = q & 3, z = q >> 2;
    int layer = z & 1, pv = z >> 1;
    const float* src = (pv ? projV : projK) + (size_t)layer * NN * KK;
    u16* dst = (pv ? pVT : pKT) + (size_t)layer * KK * NN;
    int n0 = nt * 64, k0 = kt * 64;
    int r = t >> 4, c4 = (t & 15) * 4;
#pragma unroll
    for (int i = 0; i < 4; ++i) {
      int rr = r + i * 16;
      float4 v = make_float4(0.f, 0.f, 0.f, 0.f);
      if (n0 + rr < NN) v = *reinterpret_cast<const float4*>(&src[(size_t)(n0 + rr) * KK + k0 + c4]);
      lds[c4 + 0][rr] = v.x; lds[c4 + 1][rr] = v.y; lds[c4 + 2][rr] = v.z; lds[c4 + 3][rr] = v.w;
    }
    __syncthreads();
    int kr = t >> 3, nb = (t & 7) * 8;
#pragma unroll
    for (int p = 0; p < 2; ++p) {
      int k = kr + p * 32;
      if (n0 + nb < NN) {  // NN%64==32 -> all-or-nothing per 8-chunk
        u16x8 o;
#pragma unroll
        for (int j = 0; j < 8; ++j) o[j] = f2b(lds[k][nb + j]);
        *reinterpret_cast<u16x8*>(&dst[(size_t)(k0 + k) * NN + n0 + nb]) = o;
      }
    }
  } else if (bid < 7508) {
    // ---- embed: x[b,n,d] = emb[n,d]*expr[b,n] -> bf16
    int idx8 = ((bid - 5008) * 256 + t) * 8;
    int b = idx8 / (NN * DD);
    int rem = idx8 - b * (NN * DD);
    int n = rem >> 6, d = rem & 63;
    float4 e0 = *reinterpret_cast<const float4*>(&emb[(n << 6) + d]);
    float4 e1 = *reinterpret_cast<const float4*>(&emb[(n << 6) + d + 4]);
    float s = expr[b * NN + n];
    u16x8 o;
    o[0] = f2b(e0.x * s); o[1] = f2b(e0.y * s); o[2] = f2b(e0.z * s); o[3] = f2b(e0.w * s);
    o[4] = f2b(e1.x * s); o[5] = f2b(e1.y * s); o[6] = f2b(e1.z * s); o[7] = f2b(e1.w * s);
    *reinterpret_cast<u16x8*>(&xb[idx8]) = o;
  } else if (bid < 7572) {
    // ---- weight conversion into MFMA B-fragment order
    int b2 = bid - 7508;
    int bx = b2 & 7, m = (b2 >> 3) & 3, l = b2 >> 5;
    const float* src; u16* dst; int Dout, S, CT;
    if (m == 0)      { src = Wq + l * 4096;  dst = wb + l * 4096;          Dout = 64;  S = 4;  CT = 2; }
    else if (m == 1) { src = Wo + l * 4096;  dst = wb + 8192 + l * 4096;   Dout = 64;  S = 4;  CT = 2; }
    else if (m == 2) { src = W1 + l * 16384; dst = wb + 16384 + l * 16384; Dout = 256; S = 4;  CT = 8; }
    else             { src = W2 + l * 16384; dst = wb + 49152 + l * 16384; Dout = 64;  S = 16; CT = 2; }
    int slot = bx * 256 + t;
    if (slot >= S * CT * 64) return;
    int s = slot / (CT * 64), rem = slot % (CT * 64);
    int ct = rem >> 6, lane = rem & 63;
    int hi = lane >> 5, lo = lane & 31;
    u16x8 o;
#pragma unroll
    for (int j = 0; j < 8; ++j) o[j] = f2b(src[(s * 16 + hi * 8 + j) * Dout + ct * 32 + lo]);
    *reinterpret_cast<u16x8*>(&dst[slot * 8]) = o;
  } else {
    ones[t] = 0x3F80;  // bf16 1.0, 256 entries
  }
}

// ---------------------------------------------------------------------------
// Merged: [0,625) Q = x @ Wq (32-row units/wave); [625,1877) xT transpose.
__global__ __launch_bounds__(256) void k_qxt(
    const u16* __restrict__ x, const u16* __restrict__ WB,
    u16* __restrict__ qb, u16* __restrict__ xT) {
  __shared__ u16 ldsx[64][70];
  int bid = blockIdx.x;
  int t = threadIdx.x;
  if (bid < 625) {
    int w = t >> 6, lane = t & 63;
    int lo = lane & 31, hi = lane >> 5;
    int unit = bid * 4 + w;
    bf16x8 wf[4][2];
#pragma unroll
    for (int s = 0; s < 4; ++s)
#pragma unroll
      for (int ct = 0; ct < 2; ++ct) wf[s][ct] = ldb8(&WB[((s * 2 + ct) * 64 + lane) * 8]);
    f32x16 acc[2] = {};
    int r0 = unit * 32;
#pragma unroll
    for (int s = 0; s < 4; ++s) {
      bf16x8 a = ldb8(&x[(size_t)(r0 + lo) * 64 + s * 16 + hi * 8]);
      acc[0] = mfma32(a, wf[s][0], acc[0]);
      acc[1] = mfma32(a, wf[s][1], acc[1]);
    }
#pragma unroll
    for (int reg = 0; reg < 16; ++reg) {
      int row = r0 + (reg & 3) + 8 * (reg >> 2) + 4 * hi;
      qb[(size_t)row * 64 + lo] = f2b(acc[0][reg]);
      qb[(size_t)row * 64 + 32 + lo] = f2b(acc[1][reg]);
    }
  } else {
    int v = bid - 625;
    int nt = v % 313, b = v / 313;
    int n0 = nt * 64;
    int r = t >> 4, c4 = (t & 15) * 4;
    const u16* xbp = x + (size_t)b * NN * 64;
#pragma unroll
    for (int i = 0; i < 4; ++i) {
      int rr = r + i * 16;
      u16x4 vv = {};
      if (n0 + rr < NN) vv = *reinterpret_cast<const u16x4*>(&xbp[(size_t)(n0 + rr) * 64 + c4]);
      ldsx[c4 + 0][rr] = vv[0]; ldsx[c4 + 1][rr] = vv[1];
      ldsx[c4 + 2][rr] = vv[2]; ldsx[c4 + 3][rr] = vv[3];
    }
    __syncthreads();
    int dr = t >> 3, nb = (t & 7) * 8;
    u16* xo = xT + (size_t)b * 64 * NN;
#pragma unroll
    for (int p = 0; p < 2; ++p) {
      int d = dr + p * 32;
      if (n0 + nb < NN) {
        u16x8 o;
#pragma unroll
        for (int j = 0; j < 8; ++j) o[j] = ldsx[d][nb + j];
        *reinterpret_cast<u16x8*>(&xo[(size_t)d * NN + n0 + nb]) = o;
      }
    }
  }
}

// ---------------------------------------------------------------------------
// Linformer projection partials, 4x unrolled n-loop for MLP.
// part[proj][b][c][64 d][256 k] = sum_n xT[d][n]*pT[k][n]
__global__ __launch_bounds__(256) void k_proj(
    const u16* __restrict__ xT, const u16* __restrict__ pKT_l, const u16* __restrict__ pVT_l,
    float* __restrict__ part) {
  int c = blockIdx.x, b = blockIdx.y, proj = blockIdx.z;
  const u16* P = proj ? pVT_l : pKT_l;
  int t = threadIdx.x, w = t >> 6, lane = t & 63;
  int lo = lane & 31, hi = lane >> 5;
  int d0 = (w & 1) * 32;
  int kbase = (w >> 1) * 128;
  int n0 = c * 512;
  int rem = NN - n0;
  int steps = (rem < 512 ? rem : 512) >> 4;
  const u16* xr = xT + ((size_t)b * 64 + d0 + lo) * NN;
  f32x16 acc[4] = {};
  int s = 0;
  for (; s + 4 <= steps; s += 4) {
    bf16x8 a[4]; bf16x8 bv[4][4];
#pragma unroll
    for (int u = 0; u < 4; ++u) {
      int nb = n0 + (s + u) * 16 + hi * 8;
      a[u] = ldb8(&xr[nb]);
#pragma unroll
      for (int g = 0; g < 4; ++g) bv[u][g] = ldb8(&P[(size_t)(kbase + g * 32 + lo) * NN + nb]);
    }
#pragma unroll
    for (int u = 0; u < 4; ++u)
#pragma unroll
      for (int g = 0; g < 4; ++g) acc[g] = mfma32(a[u], bv[u][g], acc[g]);
  }
  for (; s < steps; ++s) {
    int nb = n0 + s * 16 + hi * 8;
    bf16x8 a = ldb8(&xr[nb]);
#pragma unroll
    for (int g = 0; g < 4; ++g) acc[g] = mfma32(a, ldb8(&P[(size_t)(kbase + g * 32 + lo) * NN + nb]), acc[g]);
  }
  float* dst = part + ((size_t)(proj * NB + b) * 40 + c) * (64 * 256);
#pragma unroll
  for (int g = 0; g < 4; ++g)
#pragma unroll
    for (int r = 0; r < 16; ++r) {
      int d = d0 + (r & 3) + 8 * (r >> 2) + 4 * hi;
      dst[d * 256 + kbase + g * 32 + lo] = acc[g][r];
    }
}

// ---------------------------------------------------------------------------
// Reduce 40 chunk-partials + apply Wk/Wv. K-side pre-scaled by SCALE*log2e.
__global__ __launch_bounds__(256) void k_p2(
    const float* __restrict__ part, const float* __restrict__ Wk_l, const float* __restrict__ Wv_l,
    u16* __restrict__ kbuf, u16* __restrict__ vT) {
  int ks = blockIdx.x, b = blockIdx.y, proj = blockIdx.z;
  int k0 = ks * 8;
  const float* W = proj ? Wv_l : Wk_l;
  __shared__ float low[64][8];
  int t = threadIdx.x;
  const float* src = part + (size_t)(proj * NB + b) * 40 * (64 * 256);
#pragma unroll
  for (int i = 0; i < 2; ++i) {
    int idx = i * 256 + t;
    int e = idx >> 3, k = idx & 7;
    float s = 0.f;
    for (int cc = 0; cc < 40; ++cc) s += src[(size_t)cc * (64 * 256) + e * 256 + k0 + k];
    low[e][k] = s;
  }
  __syncthreads();
#pragma unroll
  for (int i = 0; i < 2; ++i) {
    int idx = i * 256 + t;
    int d = idx & 63, kk = idx >> 6;
    float a = 0.f;
#pragma unroll
    for (int e = 0; e < 64; ++e) a += low[e][kk] * W[e * 64 + d];
    if (proj == 0) {
      // fold attention scale * log2(e) into K
      kbuf[((size_t)b * KK + k0 + kk) * 64 + d] = f2b(a * 0.3606737602222409f);
    } else {
      vT[((size_t)b * 64 + d) * KK + k0 + kk] = f2b(a);
    }
  }
}

// ---------------------------------------------------------------------------
// Fused Linformer attention. Block = 32 queries x 4 heads (wave = head).
// S^T = K.Q^T; P->bf16 via v_cvt_pk + permlane32_swap; softmax denominator
// computed by the PV MFMA itself (A rows 16..31 = 1.0 read from ones buffer).
__global__ __launch_bounds__(256) void k_attn(
    const u16* __restrict__ q, const u16* __restrict__ kbuf, const u16* __restrict__ vT,
    const u16* __restrict__ ones, u16* __restrict__ ao) {
  int t = threadIdx.x, h = t >> 6, lane = t & 63;
  int lo = lane & 31, hi = lane >> 5;
  int b = blockIdx.y;
  int n0 = blockIdx.x * 32;
  const u16* qb = q + (size_t)b * NN * 64;
  const u16* kb = kbuf + (size_t)b * KK * 64 + h * 16;
  // A-operand rows 0..15 -> V^T rows (head h); rows 16..31 -> 1.0 (sum rows)
  const u16* vsrc = (lo < 16)
      ? vT + (size_t)b * 64 * KK + (size_t)(h * 16 + lo) * KK
      : ones;
  bf16x8 qf = ldb8(&qb[(size_t)(n0 + lo) * 64 + h * 16 + hi * 8]);
  f32x16 acc = {};
#pragma unroll
  for (int kt = 0; kt < 8; ++kt) {
    bf16x8 kf = ldb8(&kb[(size_t)(kt * 32 + lo) * 64 + hi * 8]);
    f32x16 z = {};
    f32x16 s = mfma32(kf, qf, z);  // S^T tile: col = query(lo), rows = 32 keys (pre-scaled)
    float e[16];
#pragma unroll
    for (int r = 0; r < 16; ++r) e[r] = __builtin_amdgcn_exp2f(s[r]);
#pragma unroll
    for (int c = 0; c < 2; ++c) {
      unsigned Aw = cvtpk(e[c * 8 + 0], e[c * 8 + 1]);
      unsigned Bw = cvtpk(e[c * 8 + 2], e[c * 8 + 3]);
      unsigned Cw = cvtpk(e[c * 8 + 4], e[c * 8 + 5]);
      unsigned Dw = cvtpk(e[c * 8 + 6], e[c * 8 + 7]);
      swap32(Aw, Cw);  // Aw -> keys {0,1}|{8,9}, Cw -> keys {4,5}|{12,13}
      swap32(Bw, Dw);
      uint4v pk; pk.x = Aw; pk.y = Bw; pk.z = Cw; pk.w = Dw;
      bf16x8 af = ldb8(&vsrc[kt * 32 + c * 16 + hi * 8]);
      acc = mfma32(af, __builtin_bit_cast(bf16x8, pk), acc);
    }
  }
  // acc rows 16..31 all hold sum_k P[k][query]; reg 8 = row 16/20.
  float inv = __builtin_amdgcn_rcpf(acc[8]);
  float o[8];
#pragma unroll
  for (int r = 0; r < 8; ++r) o[r] = acc[r] * inv;
  unsigned Aw = cvtpk(o[0], o[1]);
  unsigned Bw = cvtpk(o[2], o[3]);
  unsigned Cw = cvtpk(o[4], o[5]);
  unsigned Dw = cvtpk(o[6], o[7]);
  swap32(Aw, Cw);
  swap32(Bw, Dw);
  uint4v st; st.x = Aw; st.y = Bw; st.z = Cw; st.w = Dw;
  *reinterpret_cast<uint4v*>(&ao[(size_t)b * NN * 64 + (size_t)(n0 + lo) * 64 + h * 16 + hi * 8]) = st;
}

// ---------------------------------------------------------------------------
// Row GEMM out[M,64] = A[M,64] @ W[64,64] + bias + residual + LayerNorm.
// 32-row units per wave, grid 625.
__global__ __launch_bounds__(256) void k_oln(
    const u16* __restrict__ A, const u16* __restrict__ WB,
    const float* __restrict__ bias, const u16* __restrict__ res,
    const float* __restrict__ g, const float* __restrict__ be, u16* __restrict__ out) {
  int t = threadIdx.x, w = t >> 6, lane = t & 63;
  int lo = lane & 31, hi = lane >> 5;
  int unit = blockIdx.x * 4 + w;
  bf16x8 wf[4][2];
#pragma unroll
  for (int s = 0; s < 4; ++s)
#pragma unroll
    for (int ct = 0; ct < 2; ++ct) wf[s][ct] = ldb8(&WB[((s * 2 + ct) * 64 + lane) * 8]);
  float bia[2], gg[2], bb[2];
#pragma unroll
  for (int ct = 0; ct < 2; ++ct) {
    bia[ct] = bias[ct * 32 + lo];
    gg[ct] = g[ct * 32 + lo];
    bb[ct] = be[ct * 32 + lo];
  }
  f32x16 acc[2] = {};
  int r0 = unit * 32;
#pragma unroll
  for (int s = 0; s < 4; ++s) {
    bf16x8 a = ldb8(&A[(size_t)(r0 + lo) * 64 + s * 16 + hi * 8]);
    acc[0] = mfma32(a, wf[s][0], acc[0]);
    acc[1] = mfma32(a, wf[s][1], acc[1]);
  }
#pragma unroll
  for (int reg = 0; reg < 16; ++reg) {
    int row = r0 + (reg & 3) + 8 * (reg >> 2) + 4 * hi;
    float a0 = acc[0][reg] + bia[0] + b2f(res[(size_t)row * 64 + lo]);
    float a1 = acc[1][reg] + bia[1] + b2f(res[(size_t)row * 64 + 32 + lo]);
    float su = a0 + a1, sq = a0 * a0 + a1 * a1;
#pragma unroll
    for (int m = 1; m <= 16; m <<= 1) { su += __shfl_xor(su, m); sq += __shfl_xor(sq, m); }
    float mean = su * (1.f / 64.f);
    float var = sq * (1.f / 64.f) - mean * mean;
    float rstd = rsqrtf(var + 1e-5f);
    out[(size_t)row * 64 + lo] = f2b((a0 - mean) * rstd * gg[0] + bb[0]);
    out[(size_t)row * 64 + 32 + lo] = f2b((a1 - mean) * rstd * gg[1] + bb[1]);
  }
}

// ---------------------------------------------------------------------------
// FFN1: out[M,256] = gelu(A[M,64] @ W1[64,256] + bias).
__global__ __launch_bounds__(256, 2) void k_gemm_64_256(
    const u16* __restrict__ A, const u16* __restrict__ WB,
    const float* __restrict__ bias, u16* __restrict__ out) {
  int t = threadIdx.x, w = t >> 6, lane = t & 63;
  int lo = lane & 31, hi = lane >> 5;
  int colg = w & 1;
  int unit = blockIdx.x * 2 + (w >> 1);
  bf16x8 wf[4][4];
  float bia[4];
#pragma unroll
  for (int s = 0; s < 4; ++s)
#pragma unroll
    for (int ct = 0; ct < 4; ++ct) wf[s][ct] = ldb8(&WB[((s * 8 + colg * 4 + ct) * 64 + lane) * 8]);
#pragma unroll
  for (int ct = 0; ct < 4; ++ct) bia[ct] = bias[colg * 128 + ct * 32 + lo];
  f32x16 acc[4] = {};
  int r0 = unit * 32;
#pragma unroll
  for (int s = 0; s < 4; ++s) {
    bf16x8 a = ldb8(&A[(size_t)(r0 + lo) * 64 + s * 16 + hi * 8]);
#pragma unroll
    for (int ct = 0; ct < 4; ++ct) acc[ct] = mfma32(a, wf[s][ct], acc[ct]);
  }
#pragma unroll
  for (int ct = 0; ct < 4; ++ct) {
#pragma unroll
    for (int reg = 0; reg < 16; ++reg) {
      int row = r0 + (reg & 3) + 8 * (reg >> 2) + 4 * hi;
      float x = acc[ct][reg] + bia[ct];
      float gel = 0.5f * x * (1.f + erff(x * 0.7071067811865475f));
      out[(size_t)row * 256 + colg * 128 + ct * 32 + lo] = f2b(gel);
    }
  }
}

// ---------------------------------------------------------------------------
// FFN2: LN(A[M,256] @ W2[256,64] + bias + res). 32-row units, grid 625.
__global__ __launch_bounds__(256) void k_gemm_256_64(
    const u16* __restrict__ A, const u16* __restrict__ WB,
    const float* __restrict__ bias, const u16* __restrict__ res,
    const float* __restrict__ g, const float* __restrict__ be,
    u16* __restrict__ outb, float* __restrict__ outf) {
  int t = threadIdx.x, w = t >> 6, lane = t & 63;
  int lo = lane & 31, hi = lane >> 5;
  int unit = blockIdx.x * 4 + w;
  float bia[2], gg[2], bb[2];
#pragma unroll
  for (int ct = 0; ct < 2; ++ct) {
    bia[ct] = bias[ct * 32 + lo];
    gg[ct] = g[ct * 32 + lo];
    bb[ct] = be[ct * 32 + lo];
  }
  f32x16 acc[2] = {};
  int r0 = unit * 32;
#pragma unroll
  for (int s = 0; s < 16; ++s) {
    bf16x8 w0 = ldb8(&WB[((s * 2 + 0) * 64 + lane) * 8]);
    bf16x8 w1 = ldb8(&WB[((s * 2 + 1) * 64 + lane) * 8]);
    bf16x8 a = ldb8(&A[(size_t)(r0 + lo) * 256 + s * 16 + hi * 8]);
    acc[0] = mfma32(a, w0, acc[0]);
    acc[1] = mfma32(a, w1, acc[1]);
  }
#pragma unroll
  for (int reg = 0; reg < 16; ++reg) {
    int row = r0 + (reg & 3) + 8 * (reg >> 2) + 4 * hi;
    float a0 = acc[0][reg] + bia[0] + b2f(res[(size_t)row * 64 + lo]);
    float a1 = acc[1][reg] + bia[1] + b2f(res[(size_t)row * 64 + 32 + lo]);
    float su = a0 + a1, sq = a0 * a0 + a1 * a1;
#pragma unroll
    for (int m = 1; m <= 16; m <<= 1) { su += __shfl_xor(su, m); sq += __shfl_xor(sq, m); }
    float mean = su * (1.f / 64.f);
    float var = sq * (1.f / 64.f) - mean * mean;
    float rstd = rsqrtf(var + 1e-5f);
    float o0 = (a0 - mean) * rstd * gg[0] + bb[0];
    float o1 = (a1 - mean) * rstd * gg[1] + bb[1];
    if (outb) {
      outb[(size_t)row * 64 + lo] = f2b(o0);
      outb[(size_t)row * 64 + 32 + lo] = f2b(o1);
    }
    if (outf) {
      outf[(size_t)row * 64 + lo] = o0;
      outf[(size_t)row * 64 + 32 + lo] = o1;
    }
  }
}

// ---------------------------------------------------------------------------
extern "C" void kernel_launch(void* const* d_in, const int* in_sizes, int n_in,
                              void* d_out, int out_size, void* d_ws, size_t ws_size,
                              hipStream_t stream) {
  const float* expr = (const float*)d_in[0];
  const float* emb  = (const float*)d_in[1];
  const float* Wq   = (const float*)d_in[2];
  const float* Wk   = (const float*)d_in[3];
  const float* Wv   = (const float*)d_in[4];
  const float* projK = (const float*)d_in[5];
  const float* projV = (const float*)d_in[6];
  const float* Wo   = (const float*)d_in[7];
  const float* bo   = (const float*)d_in[8];
  const float* g1   = (const float*)d_in[9];
  const float* be1  = (const float*)d_in[10];
  const float* W1   = (const float*)d_in[11];
  const float* bf1  = (const float*)d_in[12];
  const float* W2   = (const float*)d_in[13];
  const float* bf2  = (const float*)d_in[14];
  const float* g2   = (const float*)d_in[15];
  const float* be2  = (const float*)d_in[16];
  float* out = (float*)d_out;
  char* ws = (char*)d_ws;

  // workspace layout (bytes)
  u16* xb0 = (u16*)(ws + 0);                 // 10,240,000
  u16* xb1 = (u16*)(ws + 10240000);          // 10,240,000
  u16* xb2 = (u16*)(ws + 20480000);          // 10,240,000
  u16* qb  = (u16*)(ws + 30720000);          // 10,240,000
  u16* aob = (u16*)(ws + 40960000);          // 10,240,000
  u16* hb  = (u16*)(ws + 51200000);          // 40,960,000  (FFN hidden)
  float* part = (float*)(ws + 51200000);     // 20,971,520  -- aliases hb (disjoint lifetimes)
  u16* pKT = (u16*)(ws + 92160000);          // 20,480,000 (2 layers)
  u16* pVT = (u16*)(ws + 112640000);         // 20,480,000
  u16* xTb = (u16*)(ws + 133120000);         // 10,240,000
  u16* kB  = (u16*)(ws + 143360000);         // 131,072
  u16* vTB = (u16*)(ws + 143491072);         // 131,072
  u16* wb  = (u16*)(ws + 143622144);         // 163,840
  u16* ones = (u16*)(ws + 143785984);        // 512 (bf16 1.0 x256)

  k_pre<<<7573, 256, 0, stream>>>(expr, emb, Wq, Wo, W1, W2, projK, projV,
                                  wb, pKT, pVT, xb0, ones);

  const u16* xin = xb0;
  for (int l = 0; l < 2; ++l) {
    const u16* wbq = wb + l * 4096;
    const u16* wbo = wb + 8192 + l * 4096;
    const u16* wb1 = wb + 16384 + l * 16384;
    const u16* wb2 = wb + 49152 + l * 16384;
    k_qxt<<<1877, 256, 0, stream>>>(xin, wbq, qb, xTb);
    k_proj<<<dim3(40, NB, 2), 256, 0, stream>>>(xTb, pKT + (size_t)l * KK * NN, pVT + (size_t)l * KK * NN, part);
    k_p2<<<dim3(32, NB, 2), 256, 0, stream>>>(part, Wk + l * 4096, Wv + l * 4096, kB, vTB);
    k_attn<<<dim3(625, NB), 256, 0, stream>>>(qb, kB, vTB, ones, aob);
    k_oln<<<625, 256, 0, stream>>>(aob, wbo, bo + l * 64, xin, g1 + l * 64, be1 + l * 64, xb1);
    k_gemm_64_256<<<1250, 256, 0, stream>>>(xb1, wb1, bf1 + l * 256, hb);
    k_gemm_256_64<<<625, 256, 0, stream>>>(hb, wb2, bf2 + l * 64, xb1,
                                           g2 + l * 64, be2 + l * 64,
                                           l == 0 ? xb2 : nullptr, l == 1 ? out : nullptr);
    xin = xb2;
  }
}

// Round 2
// 405.105 us; speedup vs baseline: 1.2103x; 1.0415x over previous
//
#include <hip/hip_runtime.h>

using u16 = unsigned short;
typedef __bf16 bf16x8 __attribute__((ext_vector_type(8)));
typedef u16    u16x8  __attribute__((ext_vector_type(8)));
typedef u16    u16x4  __attribute__((ext_vector_type(4)));
typedef float  f32x4  __attribute__((ext_vector_type(4)));
typedef float  f32x16 __attribute__((ext_vector_type(16)));
typedef unsigned uint4v __attribute__((ext_vector_type(4)));

#define DEV static __device__ __forceinline__

constexpr int NB = 4;          // batch
constexpr int NN = 20000;      // tokens
constexpr int DD = 64;         // model dim
constexpr int KK = 256;        // linformer K
constexpr int ROWS = NB * NN;  // 80000 flat rows

DEV float b2f(u16 u) { union { unsigned i; float f; } c; c.i = ((unsigned)u) << 16; return c.f; }
DEV u16 f2b(float f) {
  union { float f; unsigned i; } c; c.f = f;
  unsigned i = c.i + 0x7FFFu + ((c.i >> 16) & 1u);
  return (u16)(i >> 16);
}
DEV bf16x8 ldb8(const u16* p) { return *reinterpret_cast<const bf16x8*>(p); }
DEV f32x16 mfma32(bf16x8 a, bf16x8 b, f32x16 c) { return __builtin_amdgcn_mfma_f32_32x32x16_bf16(a, b, c, 0, 0, 0); }

// pack two f32 -> one u32 of 2 bf16 (elem0 = lo, elem1 = hi), RNE
DEV unsigned cvtpk(float lo, float hi) {
  unsigned r;
  asm("v_cvt_pk_bf16_f32 %0, %1, %2" : "=v"(r) : "v"(lo), "v"(hi));
  return r;
}
// exchange: a' = [a.lo32 | b.lo32], b' = [a.hi32 | b.hi32]
DEV void swap32(unsigned& a, unsigned& b) {
  auto r = __builtin_amdgcn_permlane32_swap((int)a, (int)b, false, false);
  a = (unsigned)r[0]; b = (unsigned)r[1];
}

// ---------------------------------------------------------------------------
// Merged preamble:
//  [0,2512)      transpose projK/projV -> bf16 [K][N], 128n x 64k tiles
//  [2512,5012)   embed
//  [5012,5076)   weight fragment conversion (Wq/Wo std; W1T/W2T for fused FFN)
//  [5076]        ones fill
__global__ __launch_bounds__(256) void k_pre(
    const float* __restrict__ expr, const float* __restrict__ emb,
    const float* __restrict__ Wq, const float* __restrict__ Wo,
    const float* __restrict__ W1, const float* __restrict__ W2,
    const float* __restrict__ projK, const float* __restrict__ projV,
    u16* __restrict__ wb, u16* __restrict__ pKT, u16* __restrict__ pVT,
    u16* __restrict__ xb, u16* __restrict__ ones) {
  __shared__ float lds[64][130];  // [k][n] tile, 33.3 KB
  int bid = blockIdx.x;
  int t = threadIdx.x;
  if (bid < 2512) {
    // ---- transpose [L][N][K] f32 -> [L][K][N] bf16, tile 128n x 64k
    int nt = bid % 157, q = bid / 157, kt = q & 3, z = q >> 2;
    int layer = z & 1, pv = z >> 1;
    const float* src = (pv ? projV : projK) + (size_t)layer * NN * KK;
    u16* dst = (pv ? pVT : pKT) + (size_t)layer * KK * NN;
    int n0 = nt * 128, k0 = kt * 64;
    // load: 128 rows x 64 k; thread: row n=t>>1, k-half (t&1)*32, 8 float4 in flight
    int nr = t >> 1, kh = (t & 1) * 32;
    float4 vv[8];
    bool okr = (n0 + nr < NN);
#pragma unroll
    for (int q8 = 0; q8 < 8; ++q8) {
      vv[q8] = make_float4(0.f, 0.f, 0.f, 0.f);
      if (okr) vv[q8] = *reinterpret_cast<const float4*>(&src[(size_t)(n0 + nr) * KK + k0 + kh + q8 * 4]);
    }
#pragma unroll
    for (int q8 = 0; q8 < 8; ++q8) {
      lds[kh + q8 * 4 + 0][nr] = vv[q8].x;
      lds[kh + q8 * 4 + 1][nr] = vv[q8].y;
      lds[kh + q8 * 4 + 2][nr] = vv[q8].z;
      lds[kh + q8 * 4 + 3][nr] = vv[q8].w;
    }
    __syncthreads();
    // store: 64 k-rows x 128 n; thread: nb=(t&15)*8, k=(t>>4)+p*16 -> 256B row-chunks
    int nb = (t & 15) * 8, kr = t >> 4;
#pragma unroll
    for (int p = 0; p < 4; ++p) {
      int k = kr + p * 16;
      if (n0 + nb < NN) {  // NN%128==32, nb multiple of 8 -> all-or-nothing
        u16x8 o;
#pragma unroll
        for (int j = 0; j < 8; ++j) o[j] = f2b(lds[k][nb + j]);
        *reinterpret_cast<u16x8*>(&dst[(size_t)(k0 + k) * NN + n0 + nb]) = o;
      }
    }
  } else if (bid < 5012) {
    // ---- embed: x[b,n,d] = emb[n,d]*expr[b,n] -> bf16
    int idx8 = ((bid - 2512) * 256 + t) * 8;
    int b = idx8 / (NN * DD);
    int rem = idx8 - b * (NN * DD);
    int n = rem >> 6, d = rem & 63;
    float4 e0 = *reinterpret_cast<const float4*>(&emb[(n << 6) + d]);
    float4 e1 = *reinterpret_cast<const float4*>(&emb[(n << 6) + d + 4]);
    float s = expr[b * NN + n];
    u16x8 o;
    o[0] = f2b(e0.x * s); o[1] = f2b(e0.y * s); o[2] = f2b(e0.z * s); o[3] = f2b(e0.w * s);
    o[4] = f2b(e1.x * s); o[5] = f2b(e1.y * s); o[6] = f2b(e1.z * s); o[7] = f2b(e1.w * s);
    *reinterpret_cast<u16x8*>(&xb[idx8]) = o;
  } else if (bid < 5076) {
    // ---- weight conversion into MFMA fragment orders
    int b2 = bid - 5012;
    int bx = b2 & 7, m = (b2 >> 3) & 3, l = b2 >> 5;
    int slot = bx * 256 + t;
    u16x8 o;
    if (m <= 1) {
      if (slot >= 512) return;
      int s = slot >> 7, rem = slot & 127;
      int ct = rem >> 6, lane = rem & 63;
      int hi = lane >> 5, lo = lane & 31;
      const float* src = (m == 0 ? Wq : Wo) + l * 4096;
      u16* dst = wb + (m == 0 ? 0 : 8192) + l * 4096;
#pragma unroll
      for (int j = 0; j < 8; ++j) o[j] = f2b(src[(s * 16 + hi * 8 + j) * 64 + ct * 32 + lo]);
      *reinterpret_cast<u16x8*>(&dst[slot * 8]) = o;
    } else if (m == 2) {
      // W1T: A-frag rows = f. slot=(ftile*4+s)*64+lane -> W1[d=s*16+hi*8+j][f=ftile*32+lo]
      int ftile = slot >> 8, s = (slot >> 6) & 3, lane = slot & 63;
      int hi = lane >> 5, lo = lane & 31;
      const float* src = W1 + l * 16384;
      u16* dst = wb + 16384 + l * 16384;
#pragma unroll
      for (int j = 0; j < 8; ++j) o[j] = f2b(src[(s * 16 + hi * 8 + j) * 256 + ftile * 32 + lo]);
      *reinterpret_cast<u16x8*>(&dst[slot * 8]) = o;
    } else {
      // W2T: A-frag rows = d. slot=(dtile*16+s2)*64+lane -> W2[f=s2*16+hi*8+j][d=dtile*32+lo]
      int dtile = slot >> 10, s2 = (slot >> 6) & 15, lane = slot & 63;
      int hi = lane >> 5, lo = lane & 31;
      const float* src = W2 + l * 16384;
      u16* dst = wb + 49152 + l * 16384;
#pragma unroll
      for (int j = 0; j < 8; ++j) o[j] = f2b(src[(s2 * 16 + hi * 8 + j) * 64 + dtile * 32 + lo]);
      *reinterpret_cast<u16x8*>(&dst[slot * 8]) = o;
    }
  } else {
    ones[t] = 0x3F80;  // bf16 1.0, 256 entries
  }
}

// ---------------------------------------------------------------------------
// Merged: [0,625) Q = x @ Wq (32-row units/wave); [625,1877) xT transpose.
__global__ __launch_bounds__(256) void k_qxt(
    const u16* __restrict__ x, const u16* __restrict__ WB,
    u16* __restrict__ qb, u16* __restrict__ xT) {
  __shared__ u16 ldsx[64][70];
  int bid = blockIdx.x;
  int t = threadIdx.x;
  if (bid < 625) {
    int w = t >> 6, lane = t & 63;
    int lo = lane & 31, hi = lane >> 5;
    int unit = bid * 4 + w;
    bf16x8 wf[4][2];
#pragma unroll
    for (int s = 0; s < 4; ++s)
#pragma unroll
      for (int ct = 0; ct < 2; ++ct) wf[s][ct] = ldb8(&WB[((s * 2 + ct) * 64 + lane) * 8]);
    f32x16 acc[2] = {};
    int r0 = unit * 32;
#pragma unroll
    for (int s = 0; s < 4; ++s) {
      bf16x8 a = ldb8(&x[(size_t)(r0 + lo) * 64 + s * 16 + hi * 8]);
      acc[0] = mfma32(a, wf[s][0], acc[0]);
      acc[1] = mfma32(a, wf[s][1], acc[1]);
    }
#pragma unroll
    for (int reg = 0; reg < 16; ++reg) {
      int row = r0 + (reg & 3) + 8 * (reg >> 2) + 4 * hi;
      qb[(size_t)row * 64 + lo] = f2b(acc[0][reg]);
      qb[(size_t)row * 64 + 32 + lo] = f2b(acc[1][reg]);
    }
  } else {
    int v = bid - 625;
    int nt = v % 313, b = v / 313;
    int n0 = nt * 64;
    int r = t >> 4, c4 = (t & 15) * 4;
    const u16* xbp = x + (size_t)b * NN * 64;
#pragma unroll
    for (int i = 0; i < 4; ++i) {
      int rr = r + i * 16;
      u16x4 vv = {};
      if (n0 + rr < NN) vv = *reinterpret_cast<const u16x4*>(&xbp[(size_t)(n0 + rr) * 64 + c4]);
      ldsx[c4 + 0][rr] = vv[0]; ldsx[c4 + 1][rr] = vv[1];
      ldsx[c4 + 2][rr] = vv[2]; ldsx[c4 + 3][rr] = vv[3];
    }
    __syncthreads();
    int dr = t >> 3, nb = (t & 7) * 8;
    u16* xo = xT + (size_t)b * 64 * NN;
#pragma unroll
    for (int p = 0; p < 2; ++p) {
      int d = dr + p * 32;
      if (n0 + nb < NN) {
        u16x8 o;
#pragma unroll
        for (int j = 0; j < 8; ++j) o[j] = ldsx[d][nb + j];
        *reinterpret_cast<u16x8*>(&xo[(size_t)d * NN + n0 + nb]) = o;
      }
    }
  }
}

// ---------------------------------------------------------------------------
// Linformer projection partials, 4x unrolled n-loop for MLP.
// part[proj][b][c][64 d][256 k] = sum_n xT[d][n]*pT[k][n]
__global__ __launch_bounds__(256) void k_proj(
    const u16* __restrict__ xT, const u16* __restrict__ pKT_l, const u16* __restrict__ pVT_l,
    float* __restrict__ part) {
  int c = blockIdx.x, b = blockIdx.y, proj = blockIdx.z;
  const u16* P = proj ? pVT_l : pKT_l;
  int t = threadIdx.x, w = t >> 6, lane = t & 63;
  int lo = lane & 31, hi = lane >> 5;
  int d0 = (w & 1) * 32;
  int kbase = (w >> 1) * 128;
  int n0 = c * 512;
  int rem = NN - n0;
  int steps = (rem < 512 ? rem : 512) >> 4;
  const u16* xr = xT + ((size_t)b * 64 + d0 + lo) * NN;
  f32x16 acc[4] = {};
  int s = 0;
  for (; s + 4 <= steps; s += 4) {
    bf16x8 a[4]; bf16x8 bv[4][4];
#pragma unroll
    for (int u = 0; u < 4; ++u) {
      int nb = n0 + (s + u) * 16 + hi * 8;
      a[u] = ldb8(&xr[nb]);
#pragma unroll
      for (int g = 0; g < 4; ++g) bv[u][g] = ldb8(&P[(size_t)(kbase + g * 32 + lo) * NN + nb]);
    }
#pragma unroll
    for (int u = 0; u < 4; ++u)
#pragma unroll
      for (int g = 0; g < 4; ++g) acc[g] = mfma32(a[u], bv[u][g], acc[g]);
  }
  for (; s < steps; ++s) {
    int nb = n0 + s * 16 + hi * 8;
    bf16x8 a = ldb8(&xr[nb]);
#pragma unroll
    for (int g = 0; g < 4; ++g) acc[g] = mfma32(a, ldb8(&P[(size_t)(kbase + g * 32 + lo) * NN + nb]), acc[g]);
  }
  float* dst = part + ((size_t)(proj * NB + b) * 40 + c) * (64 * 256);
#pragma unroll
  for (int g = 0; g < 4; ++g)
#pragma unroll
    for (int r = 0; r < 16; ++r) {
      int d = d0 + (r & 3) + 8 * (r >> 2) + 4 * hi;
      dst[d * 256 + kbase + g * 32 + lo] = acc[g][r];
    }
}

// ---------------------------------------------------------------------------
// Reduce 40 chunk-partials + apply Wk/Wv. K-side pre-scaled by SCALE*log2e.
__global__ __launch_bounds__(256) void k_p2(
    const float* __restrict__ part, const float* __restrict__ Wk_l, const float* __restrict__ Wv_l,
    u16* __restrict__ kbuf, u16* __restrict__ vT) {
  int ks = blockIdx.x, b = blockIdx.y, proj = blockIdx.z;
  int k0 = ks * 8;
  const float* W = proj ? Wv_l : Wk_l;
  __shared__ float low[64][8];
  int t = threadIdx.x;
  const float* src = part + (size_t)(proj * NB + b) * 40 * (64 * 256);
#pragma unroll
  for (int i = 0; i < 2; ++i) {
    int idx = i * 256 + t;
    int e = idx >> 3, k = idx & 7;
    float s = 0.f;
    for (int cc = 0; cc < 40; ++cc) s += src[(size_t)cc * (64 * 256) + e * 256 + k0 + k];
    low[e][k] = s;
  }
  __syncthreads();
#pragma unroll
  for (int i = 0; i < 2; ++i) {
    int idx = i * 256 + t;
    int d = idx & 63, kk = idx >> 6;
    float a = 0.f;
#pragma unroll
    for (int e = 0; e < 64; ++e) a += low[e][kk] * W[e * 64 + d];
    if (proj == 0) {
      kbuf[((size_t)b * KK + k0 + kk) * 64 + d] = f2b(a * 0.3606737602222409f);
    } else {
      vT[((size_t)b * 64 + d) * KK + k0 + kk] = f2b(a);
    }
  }
}

// ---------------------------------------------------------------------------
// Fused Linformer attention. Block = 32 queries x 4 heads (wave = head).
__global__ __launch_bounds__(256) void k_attn(
    const u16* __restrict__ q, const u16* __restrict__ kbuf, const u16* __restrict__ vT,
    const u16* __restrict__ ones, u16* __restrict__ ao) {
  int t = threadIdx.x, h = t >> 6, lane = t & 63;
  int lo = lane & 31, hi = lane >> 5;
  int b = blockIdx.y;
  int n0 = blockIdx.x * 32;
  const u16* qb = q + (size_t)b * NN * 64;
  const u16* kb = kbuf + (size_t)b * KK * 64 + h * 16;
  const u16* vsrc = (lo < 16)
      ? vT + (size_t)b * 64 * KK + (size_t)(h * 16 + lo) * KK
      : ones;
  bf16x8 qf = ldb8(&qb[(size_t)(n0 + lo) * 64 + h * 16 + hi * 8]);
  f32x16 acc = {};
#pragma unroll
  for (int kt = 0; kt < 8; ++kt) {
    bf16x8 kf = ldb8(&kb[(size_t)(kt * 32 + lo) * 64 + hi * 8]);
    f32x16 z = {};
    f32x16 s = mfma32(kf, qf, z);
    float e[16];
#pragma unroll
    for (int r = 0; r < 16; ++r) e[r] = __builtin_amdgcn_exp2f(s[r]);
#pragma unroll
    for (int c = 0; c < 2; ++c) {
      unsigned Aw = cvtpk(e[c * 8 + 0], e[c * 8 + 1]);
      unsigned Bw = cvtpk(e[c * 8 + 2], e[c * 8 + 3]);
      unsigned Cw = cvtpk(e[c * 8 + 4], e[c * 8 + 5]);
      unsigned Dw = cvtpk(e[c * 8 + 6], e[c * 8 + 7]);
      swap32(Aw, Cw);
      swap32(Bw, Dw);
      uint4v pk; pk.x = Aw; pk.y = Bw; pk.z = Cw; pk.w = Dw;
      bf16x8 af = ldb8(&vsrc[kt * 32 + c * 16 + hi * 8]);
      acc = mfma32(af, __builtin_bit_cast(bf16x8, pk), acc);
    }
  }
  float inv = __builtin_amdgcn_rcpf(acc[8]);
  float o[8];
#pragma unroll
  for (int r = 0; r < 8; ++r) o[r] = acc[r] * inv;
  unsigned Aw = cvtpk(o[0], o[1]);
  unsigned Bw = cvtpk(o[2], o[3]);
  unsigned Cw = cvtpk(o[4], o[5]);
  unsigned Dw = cvtpk(o[6], o[7]);
  swap32(Aw, Cw);
  swap32(Bw, Dw);
  uint4v st; st.x = Aw; st.y = Bw; st.z = Cw; st.w = Dw;
  *reinterpret_cast<uint4v*>(&ao[(size_t)b * NN * 64 + (size_t)(n0 + lo) * 64 + h * 16 + hi * 8]) = st;
}

// ---------------------------------------------------------------------------
// Row GEMM out[M,64] = A[M,64] @ W[64,64] + bias + residual + LayerNorm.
__global__ __launch_bounds__(256) void k_oln(
    const u16* __restrict__ A, const u16* __restrict__ WB,
    const float* __restrict__ bias, const u16* __restrict__ res,
    const float* __restrict__ g, const float* __restrict__ be, u16* __restrict__ out) {
  int t = threadIdx.x, w = t >> 6, lane = t & 63;
  int lo = lane & 31, hi = lane >> 5;
  int unit = blockIdx.x * 4 + w;
  bf16x8 wf[4][2];
#pragma unroll
  for (int s = 0; s < 4; ++s)
#pragma unroll
    for (int ct = 0; ct < 2; ++ct) wf[s][ct] = ldb8(&WB[((s * 2 + ct) * 64 + lane) * 8]);
  float bia[2], gg[2], bb[2];
#pragma unroll
  for (int ct = 0; ct < 2; ++ct) {
    bia[ct] = bias[ct * 32 + lo];
    gg[ct] = g[ct * 32 + lo];
    bb[ct] = be[ct * 32 + lo];
  }
  f32x16 acc[2] = {};
  int r0 = unit * 32;
#pragma unroll
  for (int s = 0; s < 4; ++s) {
    bf16x8 a = ldb8(&A[(size_t)(r0 + lo) * 64 + s * 16 + hi * 8]);
    acc[0] = mfma32(a, wf[s][0], acc[0]);
    acc[1] = mfma32(a, wf[s][1], acc[1]);
  }
#pragma unroll
  for (int reg = 0; reg < 16; ++reg) {
    int row = r0 + (reg & 3) + 8 * (reg >> 2) + 4 * hi;
    float a0 = acc[0][reg] + bia[0] + b2f(res[(size_t)row * 64 + lo]);
    float a1 = acc[1][reg] + bia[1] + b2f(res[(size_t)row * 64 + 32 + lo]);
    float su = a0 + a1, sq = a0 * a0 + a1 * a1;
#pragma unroll
    for (int m = 1; m <= 16; m <<= 1) { su += __shfl_xor(su, m); sq += __shfl_xor(sq, m); }
    float mean = su * (1.f / 64.f);
    float var = sq * (1.f / 64.f) - mean * mean;
    float rstd = rsqrtf(var + 1e-5f);
    out[(size_t)row * 64 + lo] = f2b((a0 - mean) * rstd * gg[0] + bb[0]);
    out[(size_t)row * 64 + 32 + lo] = f2b((a1 - mean) * rstd * gg[1] + bb[1]);
  }
}

// ---------------------------------------------------------------------------
// Fused FFN: LN(gelu(A@W1+b1)@W2 + b2 + A).  Wave = 32 rows, H kept in regs.
// GEMM1 computed swapped (H^T = W1T-frags x x-frags, n = lane col), gelu in
// register, cvt_pk+permlane32_swap rebuilds the GEMM2 B-operand (attention
// pattern), GEMM2 uses d-major W2T frags as A.
__global__ __launch_bounds__(256) void k_ffn(
    const u16* __restrict__ A, const u16* __restrict__ W1T, const u16* __restrict__ W2T,
    const float* __restrict__ b1, const float* __restrict__ b2,
    const float* __restrict__ g, const float* __restrict__ be,
    u16* __restrict__ outb, float* __restrict__ outf) {
  int t = threadIdx.x, w = t >> 6, lane = t & 63;
  int lo = lane & 31, hi = lane >> 5;
  int unit = blockIdx.x * 4 + w;
  int r0 = unit * 32;
  bf16x8 xf[4];
#pragma unroll
  for (int s = 0; s < 4; ++s) xf[s] = ldb8(&A[(size_t)(r0 + lo) * 64 + s * 16 + hi * 8]);
  f32x16 oacc[2] = {};
#pragma unroll
  for (int ft = 0; ft < 8; ++ft) {
    f32x16 hacc = {};
#pragma unroll
    for (int s = 0; s < 4; ++s)
      hacc = mfma32(ldb8(&W1T[((ft * 4 + s) * 64 + lane) * 8]), xf[s], hacc);
    // bias in D-row chunks: rows for regs g4*4..g4*4+3 are 8*g4+4*hi+0..3
    float4 bb[4];
#pragma unroll
    for (int g4 = 0; g4 < 4; ++g4)
      bb[g4] = *reinterpret_cast<const float4*>(&b1[ft * 32 + g4 * 8 + 4 * hi]);
    float e[16];
#pragma unroll
    for (int r = 0; r < 16; ++r) {
      float z = hacc[r] + bb[r >> 2][r & 3];
      e[r] = 0.5f * z * (1.f + erff(z * 0.7071067811865475f));
    }
#pragma unroll
    for (int c = 0; c < 2; ++c) {
      unsigned Aw = cvtpk(e[c * 8 + 0], e[c * 8 + 1]);
      unsigned Bw = cvtpk(e[c * 8 + 2], e[c * 8 + 3]);
      unsigned Cw = cvtpk(e[c * 8 + 4], e[c * 8 + 5]);
      unsigned Dw = cvtpk(e[c * 8 + 6], e[c * 8 + 7]);
      swap32(Aw, Cw);
      swap32(Bw, Dw);
      uint4v pk; pk.x = Aw; pk.y = Bw; pk.z = Cw; pk.w = Dw;
      bf16x8 pf = __builtin_bit_cast(bf16x8, pk);
#pragma unroll
      for (int dt = 0; dt < 2; ++dt)
        oacc[dt] = mfma32(ldb8(&W2T[((dt * 16 + ft * 2 + c) * 64 + lane) * 8]), pf, oacc[dt]);
    }
  }
  // epilogue: lane owns row n = r0+lo; regs+hi enumerate d in chunks of 4.
  int n = r0 + lo;
  float su = 0.f, sq = 0.f;
#pragma unroll
  for (int dt = 0; dt < 2; ++dt) {
#pragma unroll
    for (int m4 = 0; m4 < 4; ++m4) {
      int d0 = dt * 32 + m4 * 8 + 4 * hi;
      u16x4 rv = *reinterpret_cast<const u16x4*>(&A[(size_t)n * 64 + d0]);
      float4 b2v = *reinterpret_cast<const float4*>(&b2[d0]);
#pragma unroll
      for (int j = 0; j < 4; ++j) {
        int r = m4 * 4 + j;
        float val = oacc[dt][r] + b2v[j] + b2f(rv[j]);
        oacc[dt][r] = val;
        su += val; sq += val * val;
      }
    }
  }
  su += __shfl_xor(su, 32);
  sq += __shfl_xor(sq, 32);
  float mean = su * (1.f / 64.f);
  float var = sq * (1.f / 64.f) - mean * mean;
  float rstd = rsqrtf(var + 1e-5f);
#pragma unroll
  for (int dt = 0; dt < 2; ++dt) {
#pragma unroll
    for (int m4 = 0; m4 < 4; ++m4) {
      int d0 = dt * 32 + m4 * 8 + 4 * hi;
      float4 gv = *reinterpret_cast<const float4*>(&g[d0]);
      float4 bv = *reinterpret_cast<const float4*>(&be[d0]);
      float q0 = (oacc[dt][m4 * 4 + 0] - mean) * rstd * gv.x + bv.x;
      float q1 = (oacc[dt][m4 * 4 + 1] - mean) * rstd * gv.y + bv.y;
      float q2 = (oacc[dt][m4 * 4 + 2] - mean) * rstd * gv.z + bv.z;
      float q3 = (oacc[dt][m4 * 4 + 3] - mean) * rstd * gv.w + bv.w;
      if (outb) {
        unsigned w0 = cvtpk(q0, q1), w1 = cvtpk(q2, q3);
        u16x4 st = __builtin_bit_cast(u16x4, make_uint2(w0, w1));
        *reinterpret_cast<u16x4*>(&outb[(size_t)n * 64 + d0]) = st;
      }
      if (outf) {
        *reinterpret_cast<float4*>(&outf[(size_t)n * 64 + d0]) = make_float4(q0, q1, q2, q3);
      }
    }
  }
}

// ---------------------------------------------------------------------------
extern "C" void kernel_launch(void* const* d_in, const int* in_sizes, int n_in,
                              void* d_out, int out_size, void* d_ws, size_t ws_size,
                              hipStream_t stream) {
  const float* expr = (const float*)d_in[0];
  const float* emb  = (const float*)d_in[1];
  const float* Wq   = (const float*)d_in[2];
  const float* Wk   = (const float*)d_in[3];
  const float* Wv   = (const float*)d_in[4];
  const float* projK = (const float*)d_in[5];
  const float* projV = (const float*)d_in[6];
  const float* Wo   = (const float*)d_in[7];
  const float* bo   = (const float*)d_in[8];
  const float* g1   = (const float*)d_in[9];
  const float* be1  = (const float*)d_in[10];
  const float* W1   = (const float*)d_in[11];
  const float* bf1  = (const float*)d_in[12];
  const float* W2   = (const float*)d_in[13];
  const float* bf2  = (const float*)d_in[14];
  const float* g2   = (const float*)d_in[15];
  const float* be2  = (const float*)d_in[16];
  float* out = (float*)d_out;
  char* ws = (char*)d_ws;

  // workspace layout (bytes)
  u16* xb0 = (u16*)(ws + 0);                 // 10,240,000
  u16* xb1 = (u16*)(ws + 10240000);          // 10,240,000
  u16* xb2 = (u16*)(ws + 20480000);          // 10,240,000
  u16* qb  = (u16*)(ws + 30720000);          // 10,240,000
  u16* aob = (u16*)(ws + 40960000);          // 10,240,000
  float* part = (float*)(ws + 51200000);     // 20,971,520
  u16* pKT = (u16*)(ws + 92160000);          // 20,480,000 (2 layers)
  u16* pVT = (u16*)(ws + 112640000);         // 20,480,000
  u16* xTb = (u16*)(ws + 133120000);         // 10,240,000
  u16* kB  = (u16*)(ws + 143360000);         // 131,072
  u16* vTB = (u16*)(ws + 143491072);         // 131,072
  u16* wb  = (u16*)(ws + 143622144);         // 163,840
  u16* ones = (u16*)(ws + 143785984);        // 512 (bf16 1.0 x256)

  k_pre<<<5077, 256, 0, stream>>>(expr, emb, Wq, Wo, W1, W2, projK, projV,
                                  wb, pKT, pVT, xb0, ones);

  const u16* xin = xb0;
  for (int l = 0; l < 2; ++l) {
    const u16* wbq = wb + l * 4096;
    const u16* wbo = wb + 8192 + l * 4096;
    const u16* wb1 = wb + 16384 + l * 16384;
    const u16* wb2 = wb + 49152 + l * 16384;
    k_qxt<<<1877, 256, 0, stream>>>(xin, wbq, qb, xTb);
    k_proj<<<dim3(40, NB, 2), 256, 0, stream>>>(xTb, pKT + (size_t)l * KK * NN, pVT + (size_t)l * KK * NN, part);
    k_p2<<<dim3(32, NB, 2), 256, 0, stream>>>(part, Wk + l * 4096, Wv + l * 4096, kB, vTB);
    k_attn<<<dim3(625, NB), 256, 0, stream>>>(qb, kB, vTB, ones, aob);
    k_oln<<<625, 256, 0, stream>>>(aob, wbo, bo + l * 64, xin, g1 + l * 64, be1 + l * 64, xb1);
    k_ffn<<<625, 256, 0, stream>>>(xb1, wb1, wb2, bf1 + l * 256, bf2 + l * 64,
                                   g2 + l * 64, be2 + l * 64,
                                   l == 0 ? xb2 : nullptr, l == 1 ? out : nullptr);
    xin = xb2;
  }
}